// Round 18
// baseline (530.064 us; speedup 1.0000x reference)
//
#include <hip/hip_runtime.h>

// NNMF fused: B=8192, NIN=3072, NOUT=512, 5 iterations.
// R24: 512 blocks x 16 rows -> 2 co-resident 512-thread blocks/CU.
//  R23 re-confirmed R18 (main 235 us). Counters show NO hw roofline
//  (MFMA 20%, HBM 10%, L2 43%); diagnosed bottleneck = barrier lockstep at
//  2 waves/SIMD. R19's 1024-thr attempt died on the allocator's 64-VGPR
//  target; this keeps the PROVEN 512-thread block shape and doubles
//  occupancy via 2 independent blocks/CU (independent barriers -> when
//  block A drains at a barrier, block B issues).
//  Sizing: per-block LDS ~56 KB, deliberately >53.3 KB (h8_lds oversized)
//  so the occupancy calc pins exactly 2 blocks/CU -> compiler VGPR target
//  128 (its measured sticky point), enforced by __launch_bounds__(512,2)
//  (R7-proven cap). Live set shrinks (tacc 16, single d0) -> fits.
//  W stream/CU doubles to ~48 B/cy < 56 B/cy L2 share (W is L2-resident).
//  Numerics byte-identical to R18; prep_all = R18 verbatim.

#define NIN 3072
#define NOUT 512

using f32x4 = __attribute__((ext_vector_type(4))) float;
using i32x8 = __attribute__((ext_vector_type(8))) int;

union frag32 { i32x8 v; uint4 q[2]; };

// A = fp8 e4m3, B = fp8 e4m3, scales = 2^0
#define MFMA128(A, B, C) \
    __builtin_amdgcn_mfma_scale_f32_16x16x128_f8f6f4( \
        (A), (B), (C), 0, 0, 0, (int)0x7f7f7f7f, 0, (int)0x7f7f7f7f)
// A = fp8 e4m3 (cbsz=0), B = fp6 e2m3 (blgp=2), scales = 2^0
#define MFMA128_F6(A, B, C) \
    __builtin_amdgcn_mfma_scale_f32_16x16x128_f8f6f4( \
        (A), (B), (C), 0, 2, 0, (int)0x7f7f7f7f, 0, (int)0x7f7f7f7f)

__device__ __forceinline__ unsigned short f2bf(float f) {
    unsigned int u = __builtin_bit_cast(unsigned int, f);
    return (unsigned short)((u + 0x7fffu + ((u >> 16) & 1u)) >> 16);  // RNE
}
__device__ __forceinline__ float bf2f(unsigned short s) {
    unsigned int u = ((unsigned int)s) << 16;
    return __builtin_bit_cast(float, u);
}

// e2m3 encode of nonnegative p (caller guarantees p <= 7.75)
__device__ __forceinline__ unsigned enc_fp6(float p) {
    if (p < 1.9375f) {                 // denormal + e=1: step 0.125, codes 0..15
        int q = (int)rintf(p * 8.0f);
        return (unsigned)q;
    }
    if (p < 3.875f) {                  // e=2: step 0.25, codes 16..23
        int m = (int)rintf((p - 2.0f) * 4.0f);
        return (m > 7) ? 24u : (16u + (unsigned)m);
    }
    int m = (int)rintf((p - 4.0f) * 2.0f);  // e=3: step 0.5, codes 24..31
    if (m > 7) m = 7;
    return 24u + (unsigned)m;
}

// load a 24-byte fp6 fragment (8B-aligned) into the low 6 dwords
__device__ __forceinline__ void load6(frag32& f, const unsigned char* p) {
    const uint2* q = reinterpret_cast<const uint2*>(p);
    uint2 a = q[0], b = q[1], c = q[2];
    f.v = (i32x8){(int)a.x, (int)a.y, (int)b.x, (int)b.y, (int)c.x, (int)c.y, 0, 0};
}

// LDS-only barrier: cross-wave deps in the slot loop are LDS-only; global
// prefetches stay in flight (consumed by issuing wave, compiler inserts vmcnt).
#define LDS_BARRIER() do {                                   \
    asm volatile("s_waitcnt lgkmcnt(0)" ::: "memory");       \
    __builtin_amdgcn_s_barrier();                            \
    asm volatile("" ::: "memory");                           \
} while (0)

// ---------------------------------------------------------------------------
// prep_all: one launch, 8672 blocks x 256 threads.  (R18 verbatim)
//   blocks [0,8192)     : per-row x normalize (x16 pre-scale) -> bf16 X2
//   blocks [8192,8576)  : W -> W2 (fp8 x4096) / W1 (fp6 e2m3 x8192)
//   blocks [8576,8672)  : d0inv[k] = 1/(sum_n h0[n]*W[n][k] + 1e-20)  (exact fp32)
// K=128 fragment layouts (lane l holds 32 contiguous contraction elements,
// k = (l>>4)*32 + j):
//   W2 (Phase B B-op, fp8 32B): byte = ((s*32 + w*4 + nt)*64 + l)*32 + j
//     element: n = w*64 + nt*16 + (l&15), k = s*128 + (l>>4)*32 + j
//   W1 (Phase A B-op, fp6 24B): frag = ((s*8 + w)*4 + c)*64 + l, byte = frag*24,
//     element j at bits [6j+5:6j]: kout = s*128 + w*16 + (l&15), n = c*128 + (l>>4)*32 + j
// ---------------------------------------------------------------------------
__global__ void prep_all(const float* __restrict__ x,
                         const float* __restrict__ W,
                         const float* __restrict__ h_init,
                         unsigned short* __restrict__ X2,
                         unsigned char* __restrict__ W1,
                         unsigned char* __restrict__ W2,
                         float* __restrict__ d0inv) {
    __shared__ float wsum[4];
    __shared__ float dred[8][32];
    const int bb = blockIdx.x;
    const int t  = threadIdx.x;

    if (bb < 8192) {
        // ---- x row normalize -> bf16, pre-scaled x16 (exact: power of 2)
        const int b = bb;
        const float4* r4 = reinterpret_cast<const float4*>(x + (size_t)b * NIN);
        float s = 0.f;
        float4 v0 = r4[t], v1 = r4[t + 256], v2 = r4[t + 512];
        s = v0.x + v0.y + v0.z + v0.w + v1.x + v1.y + v1.z + v1.w + v2.x + v2.y + v2.z + v2.w;
        #pragma unroll
        for (int off = 32; off > 0; off >>= 1) s += __shfl_down(s, off, 64);
        int w = t >> 6, l = t & 63;
        if (l == 0) wsum[w] = s;
        __syncthreads();
        float inv = 16.0f / (wsum[0] + wsum[1] + wsum[2] + wsum[3] + 1e-20f);
        unsigned short* orow = X2 + (size_t)b * NIN;
        #pragma unroll
        for (int c = 0; c < 3; ++c) {
            float4 v = (c == 0) ? v0 : (c == 1) ? v1 : v2;
            ushort4 o;
            o.x = f2bf(v.x * inv); o.y = f2bf(v.y * inv);
            o.z = f2bf(v.z * inv); o.w = f2bf(v.w * inv);
            *reinterpret_cast<ushort4*>(orow + (t + c * 256) * 4) = o;
        }
    } else if (bb < 8192 + 384) {
        int tt = (bb - 8192) * 256 + t;       // 0 .. 98303
        if (tt < 49152) {
            // ---- W2 fp8 x4096
            int l = tt & 63, g = tt >> 6;
            int s = g >> 5, rem = g & 31, w = rem >> 2, nt = rem & 3;
            int n = w * 64 + nt * 16 + (l & 15);
            int kbase = s * 128 + ((l >> 4) << 5);
            const float* src = W + (size_t)n * NIN + kbase;
            unsigned int words[8];
            #pragma unroll
            for (int q = 0; q < 8; ++q) {
                float v0 = src[q * 4 + 0] * 4096.0f, v1 = src[q * 4 + 1] * 4096.0f;
                float v2 = src[q * 4 + 2] * 4096.0f, v3 = src[q * 4 + 3] * 4096.0f;
                int pk = __builtin_amdgcn_cvt_pk_fp8_f32(v0, v1, 0, false);
                pk     = __builtin_amdgcn_cvt_pk_fp8_f32(v2, v3, pk, true);
                words[q] = (unsigned int)pk;
            }
            uint4* dst = reinterpret_cast<uint4*>(W2 + (size_t)tt * 32);
            dst[0] = *reinterpret_cast<uint4*>(&words[0]);
            dst[1] = *reinterpret_cast<uint4*>(&words[4]);
        } else {
            // ---- W1 fp6 e2m3 x8192 (24 B per fragment)
            int u = tt - 49152;
            int l = u & 63, g = u >> 6;
            int c = g & 3, sw = g >> 2;
            int w = sw & 7, s = sw >> 3;
            int kout = s * 128 + w * 16 + (l & 15);
            int nbase = c * 128 + ((l >> 4) << 5);
            float v[32];
            #pragma unroll
            for (int j = 0; j < 32; ++j)
                v[j] = W[(size_t)(nbase + j) * NIN + kout] * 8192.0f;
            unsigned int dw[6] = {0, 0, 0, 0, 0, 0};
            #pragma unroll
            for (int j = 0; j < 32; ++j) {
                unsigned c6 = enc_fp6(v[j]);
                int bit = 6 * j, di = bit >> 5, off = bit & 31;
                dw[di] |= c6 << off;
                if (off > 26) dw[di + 1] |= c6 >> (32 - off);
            }
            uint2* d2 = reinterpret_cast<uint2*>(W1 + (size_t)u * 24);
            d2[0] = make_uint2(dw[0], dw[1]);
            d2[1] = make_uint2(dw[2], dw[3]);
            d2[2] = make_uint2(dw[4], dw[5]);
        }
    } else {
        // ---- d0inv: block owns 32 k-cols; thread (kid = t&31, nsub = t>>5)
        int kb = bb - 8576;                   // 0..95
        int kid = t & 31, nsub = t >> 5;      // 8 n-chunks of 64
        int k = kb * 32 + kid;
        int n0 = nsub * 64;
        float s = 0.f;
        const float* p = W + (size_t)n0 * NIN + k;
        #pragma unroll 8
        for (int n = 0; n < 64; ++n) s += h_init[n0 + n] * p[(size_t)n * NIN];
        dred[nsub][kid] = s;
        __syncthreads();
        if (t < 32) {
            float sm = 1e-20f;
            #pragma unroll
            for (int j = 0; j < 8; ++j) sm += dred[j][t];
            d0inv[kb * 32 + t] = 1.0f / sm;
        }
    }
}

// ---------------------------------------------------------------------------
// Main kernel. 512 blocks x 512 threads (8 waves), 16 rows/block, 2 blocks/CU.
// R18 two-barrier slot structure, halved M. h master in LDS.
// Phase A: h fp8 x W1 fp6 (1 M-tile, 4 MFMA/wave/slot).
// Phase B: r fp8 x W2 fp8 (4 n-tiles, 4 MFMA/wave/slot).
// ---------------------------------------------------------------------------
__global__ __launch_bounds__(512, 2) void nnmf_main(
    const unsigned short* __restrict__ X2,
    const unsigned char* __restrict__ W1,
    const unsigned char* __restrict__ W2,
    const float* __restrict__ d0inv,
    const float* __restrict__ h_init,
    float* __restrict__ out)
{
    // NOTE: h8_lds kept at 32 rows (only 16 used) so total LDS ~55.8 KB sits
    // in (53.3, 80] KB -> occupancy calc pins exactly 2 blocks/CU -> the
    // compiler's VGPR budget is 128 (not 85 for a 3-block target).
    __shared__ unsigned char  h8_lds[32 * 528];   // 16.9 KB (fp8 h, x256; rows 0-15 used)
    __shared__ float          h32_lds[16 * 516];  // 33.0 KB (fp32 h master)
    __shared__ unsigned short x_lds[16 * 136];    //  4.3 KB
    __shared__ unsigned char  r8_lds[16 * 144];   //  2.3 KB (fp8 r, stride 144B)
    __shared__ float red[8][16];                  //  0.5 KB
    // total ~55.9 KB -> 2 blocks/CU

    const int tid = threadIdx.x;
    const int w  = tid >> 6;        // wave 0..7
    const int l  = tid & 63;
    const int lo = l & 15;
    const int hi = l >> 4;          // 0..3
    const int b0 = blockIdx.x * 16;

    // fp32 h master init (LDS; each (row,col) owned by one thread at boundary)
    for (int idx = tid; idx < 16 * 512; idx += 512) {
        int r = idx >> 9, c = idx & 511;
        h32_lds[r * 516 + c] = h_init[c];
    }

    // x staging: thread -> (row = tid>>5, 8B chunk xcc = tid&31)
    const int xrow = tid >> 5, xcc = tid & 31;
    const uint2* xg = reinterpret_cast<const uint2*>(X2 + (size_t)(b0 + xrow) * NIN) + xcc;
    unsigned short* xdst = &x_lds[xrow * 136 + xcc * 4];

    // W pointers
    const unsigned char* w1base = W1 + ((size_t)(w * 4) * 64 + l) * 24;  // +s*49152 +c*1536 (fp6)
    const unsigned char* w2base = W2 + (size_t)w * 8192 + (size_t)l * 32; // +s*65536 +nt*2048 (fp8)

    // prime pipeline: x[0] -> LDS, x[1] -> reg
    *reinterpret_cast<uint2*>(xdst) = xg[0];
    uint2 xnext = xg[32];
    frag32 w1buf[4];                // Phase A B-frags fp6 (valid from it0 s==23 on)
    __syncthreads();

    const float DSCL = 4.76837158203125e-07f;  // 2^-21: undo h x2^8 * W1 x2^13
    const float TS   = 1.0f / 65536.0f;        // 2^-16: undo W2 x2^12 and x-r x2^4
    f32x4 tacc[4];

    for (int it = 0; it < 5; ++it) {
        #pragma unroll
        for (int nt = 0; nt < 4; ++nt)
            tacc[nt] = (f32x4){0.f, 0.f, 0.f, 0.f};

        for (int s = 0; s < 24; ++s) {
            const int sn  = (s + 1 == 24) ? 0 : s + 1;
            const int sn2 = (s + 2 >= 24) ? (s + 2 - 24) : s + 2;

            // ---- issue W2[s] loads (4 x 32B fp8 frags; consumed after barrier A)
            frag32 w2v[4];
            {
                const unsigned char* w2p = w2base + (size_t)s * 65536;
                #pragma unroll
                for (int nt = 0; nt < 4; ++nt) {
                    const uint4* p = reinterpret_cast<const uint4*>(w2p + nt * 2048);
                    w2v[nt].q[0] = p[0];
                    w2v[nt].q[1] = p[1];
                }
            }

            f32x4 d0 = {0,0,0,0};
            float dv = 0.f;
            if (it == 0) {
                dv = d0inv[s * 128 + w * 16 + lo];   // exact it0 denom reciprocal
            } else {
                // ---- Phase A: h fp8 (A, rows 0-15) x W1 fp6 (B)
                #pragma unroll
                for (int c = 0; c < 4; ++c) {
                    frag32 ha;
                    const uint4* p = reinterpret_cast<const uint4*>(
                        &h8_lds[lo * 528 + c * 128 + hi * 32]);
                    ha.q[0] = p[0]; ha.q[1] = p[1];
                    d0 = MFMA128_F6(ha.v, w1buf[c].v, d0);
                }
            }

            // ---- r = x * rcp(denom + eps) -> fp8 in r8_lds  (x pre-scaled x16)
            #pragma unroll
            for (int i = 0; i < 4; ++i) {
                int row0 = hi * 4 + i;
                float x0 = bf2f(x_lds[row0 * 136 + w * 16 + lo]);
                float r0;
                if (it == 0) r0 = x0 * dv;
                else         r0 = x0 * __builtin_amdgcn_rcpf(fmaf(d0[i], DSCL, 1e-20f));
                int c0 = __builtin_amdgcn_cvt_pk_fp8_f32(r0, r0, 0, false);
                r8_lds[row0 * 144 + w * 16 + lo] = (unsigned char)(c0 & 0xff);
            }
            LDS_BARRIER();   // barrier A (LDS-only: global prefetches stay in flight)

            // ---- Phase B: r8 frag (fp8) x w2v (fp8)
            frag32 ra0;
            {
                const uint4* p0 = reinterpret_cast<const uint4*>(&r8_lds[lo * 144 + hi * 32]);
                ra0.q[0] = p0[0]; ra0.q[1] = p0[1];
            }
            #pragma unroll
            for (int nt = 0; nt < 2; ++nt)
                tacc[nt] = MFMA128(ra0.v, w2v[nt].v, tacc[nt]);

            // ---- reload w1buf = W1[sn] fp6 (skip during it0 except last slot)
            if (it > 0 || s == 23) {
                const unsigned char* w1p = w1base + (size_t)sn * 49152;
                #pragma unroll
                for (int c = 0; c < 4; ++c)
                    load6(w1buf[c], w1p + c * 1536);
            }

            #pragma unroll
            for (int nt = 2; nt < 4; ++nt)
                tacc[nt] = MFMA128(ra0.v, w2v[nt].v, tacc[nt]);

            // ---- stage x[s+1] (loaded last slot), issue x[s+2]
            *reinterpret_cast<uint2*>(xdst) = xnext;
            xnext = xg[(size_t)sn2 * 32];
            LDS_BARRIER();   // barrier B
        }

        // ---- boundary: h_new = normalize(h * (1 + t*2^-16)), fp32 master in LDS
        float hv_[4][4];
        float p[4];
        #pragma unroll
        for (int i = 0; i < 4; ++i) p[i] = 0.f;

        #pragma unroll
        for (int nt = 0; nt < 4; ++nt)
            #pragma unroll
            for (int i = 0; i < 4; ++i) {
                int row = hi * 4 + i;
                int col = w * 64 + nt * 16 + lo;
                float hv = h32_lds[row * 516 + col];
                float v = hv * (1.f + tacc[nt][i] * TS);  // EPSILON_0 = 1
                hv_[nt][i] = v;
                p[i] += v;
            }
        #pragma unroll
        for (int mask = 1; mask < 16; mask <<= 1)
            #pragma unroll
            for (int i = 0; i < 4; ++i)
                p[i] += __shfl_xor(p[i], mask, 64);
        if (lo == 0) {
            #pragma unroll
            for (int i = 0; i < 4; ++i)
                red[w][hi * 4 + i] = p[i];
        }
        __syncthreads();
        float inv[4];
        #pragma unroll
        for (int i = 0; i < 4; ++i) {
            int row = hi * 4 + i;
            float S = 0.f;
            #pragma unroll
            for (int ww = 0; ww < 8; ++ww) S += red[ww][row];
            inv[i] = 1.f / (S + 1e-20f);
        }

        if (it < 4) {
            #pragma unroll
            for (int nt = 0; nt < 4; ++nt)
                #pragma unroll
                for (int i = 0; i < 4; ++i) {
                    int row = hi * 4 + i;
                    int col = w * 64 + nt * 16 + lo;
                    float hv = hv_[nt][i] * inv[i];
                    h32_lds[row * 516 + col] = hv;
                    int c = __builtin_amdgcn_cvt_pk_fp8_f32(hv * 256.0f, hv * 256.0f, 0, false);
                    h8_lds[row * 528 + col] = (unsigned char)(c & 0xff);
                }
            __syncthreads();
        } else {
            #pragma unroll
            for (int nt = 0; nt < 4; ++nt)
                #pragma unroll
                for (int i = 0; i < 4; ++i) {
                    int row = hi * 4 + i;
                    int col = w * 64 + nt * 16 + lo;
                    out[(size_t)(b0 + row) * 512 + col] = hv_[nt][i] * inv[i];
                }
        }
    }
}

extern "C" void kernel_launch(void* const* d_in, const int* in_sizes, int n_in,
                              void* d_out, int out_size, void* d_ws, size_t ws_size,
                              hipStream_t stream) {
    const float* x   = (const float*)d_in[0];   // [8192][3072]
    const float* wgt = (const float*)d_in[1];   // [512][3072]
    const float* h0  = (const float*)d_in[2];   // [512]
    float* out = (float*)d_out;

    // ws: X2 bf16 50,331,648 | W1 fp6 1,179,648 | W2 fp8 1,572,864 | d0inv 12,288
    unsigned short* X2 = (unsigned short*)d_ws;
    unsigned char*  W1 = (unsigned char*)((char*)d_ws + 50331648);
    unsigned char*  W2 = (unsigned char*)((char*)d_ws + 51511296);
    float* d0inv       = (float*)((char*)d_ws + 53084160);

    prep_all<<<8672, 256, 0, stream>>>(x, wgt, h0, X2, W1, W2, d0inv);
    nnmf_main<<<512, 512, 0, stream>>>(X2, W1, W2, d0inv, h0, out);
}

// Round 19
// 380.942 us; speedup vs baseline: 1.3915x; 1.3915x over previous
//
#include <hip/hip_runtime.h>

// NNMF fused: B=8192, NIN=3072, NOUT=512, 5 iterations.
// FINAL (R25) = R18 verbatim -- twice-reproduced session best:
//   main 234.2/235.0 us, total 381.3/381.6 us, absmax 3.05e-5.
// Session map (18 measured variants, 568 -> 381 us total):
//   WINS: MX K=128 fp8 MFMA (R11, -73us main); register-economy (h master
//     in LDS, minimal Phase-A transients; R14, -15us); fp6 e2m3 W1 (R18,
//     -6us); fused single-launch prep (R9/R10, -40us total).
//   SCHEDULING: all variants regressed (R8 fused region +54, R12 SS2 +11,
//     R13 DMA+swizzle +74, R15 mid-phase reload +34, R16 K=256 +19) ->
//     two-barrier slot rhythm with loads at region tops is the
//     compiler-cooperative local optimum.
//   OCCUPANCY: falsified on all 3 axes -- VGPR attrs ignored (R9/R10,
//     remat pins 128), 1024-thr spills (R19, 64-reg target, 287MB scratch),
//     512x16-row grid ran as 2 sequential passes (R24, occupancy stuck 23%).
//     R24's arithmetic (194us for half work = 82% of full slot) proves the
//     slot is ~80% fixed overhead -- structural, not pipe-bound.
//   NUMERICS: fp6 W2 fails (R17: error enters t as sqrt(3072)-term sum,
//     1.9e-4); fp6 W1 safe (denom-damped ~50x). fp32-x paths regress main
//     more than they save prep (R21/R22: L3 eviction, dual-path codegen).
// Structure: 256 blk x 512 thr, 32 rows/blk, 1 blk/CU; two-barrier slots;
// h fp32 master in LDS (boundary-only); Phase A = h fp8 x W1 fp6 (x2^13,
// blgp=2); Phase B = r fp8 x W2 fp8 (x2^12); exact-it0 d0inv; x bf16 x16.

#define NIN 3072
#define NOUT 512

using f32x4 = __attribute__((ext_vector_type(4))) float;
using i32x8 = __attribute__((ext_vector_type(8))) int;

union frag32 { i32x8 v; uint4 q[2]; };

// A = fp8 e4m3, B = fp8 e4m3, scales = 2^0
#define MFMA128(A, B, C) \
    __builtin_amdgcn_mfma_scale_f32_16x16x128_f8f6f4( \
        (A), (B), (C), 0, 0, 0, (int)0x7f7f7f7f, 0, (int)0x7f7f7f7f)
// A = fp8 e4m3 (cbsz=0), B = fp6 e2m3 (blgp=2), scales = 2^0
#define MFMA128_F6(A, B, C) \
    __builtin_amdgcn_mfma_scale_f32_16x16x128_f8f6f4( \
        (A), (B), (C), 0, 2, 0, (int)0x7f7f7f7f, 0, (int)0x7f7f7f7f)

__device__ __forceinline__ unsigned short f2bf(float f) {
    unsigned int u = __builtin_bit_cast(unsigned int, f);
    return (unsigned short)((u + 0x7fffu + ((u >> 16) & 1u)) >> 16);  // RNE
}
__device__ __forceinline__ float bf2f(unsigned short s) {
    unsigned int u = ((unsigned int)s) << 16;
    return __builtin_bit_cast(float, u);
}

// e2m3 encode of nonnegative p (caller guarantees p <= 7.75)
__device__ __forceinline__ unsigned enc_fp6(float p) {
    if (p < 1.9375f) {                 // denormal + e=1: step 0.125, codes 0..15
        int q = (int)rintf(p * 8.0f);
        return (unsigned)q;
    }
    if (p < 3.875f) {                  // e=2: step 0.25, codes 16..23
        int m = (int)rintf((p - 2.0f) * 4.0f);
        return (m > 7) ? 24u : (16u + (unsigned)m);
    }
    int m = (int)rintf((p - 4.0f) * 2.0f);  // e=3: step 0.5, codes 24..31
    if (m > 7) m = 7;
    return 24u + (unsigned)m;
}

// load a 24-byte fp6 fragment (8B-aligned) into the low 6 dwords
__device__ __forceinline__ void load6(frag32& f, const unsigned char* p) {
    const uint2* q = reinterpret_cast<const uint2*>(p);
    uint2 a = q[0], b = q[1], c = q[2];
    f.v = (i32x8){(int)a.x, (int)a.y, (int)b.x, (int)b.y, (int)c.x, (int)c.y, 0, 0};
}

// LDS-only barrier: cross-wave deps in the slot loop are LDS-only; global
// prefetches stay in flight (consumed by issuing wave, compiler inserts vmcnt).
#define LDS_BARRIER() do {                                   \
    asm volatile("s_waitcnt lgkmcnt(0)" ::: "memory");       \
    __builtin_amdgcn_s_barrier();                            \
    asm volatile("" ::: "memory");                           \
} while (0)

// ---------------------------------------------------------------------------
// prep_all: one launch, 8672 blocks x 256 threads.
//   blocks [0,8192)     : per-row x normalize (x16 pre-scale) -> bf16 X2
//   blocks [8192,8576)  : W -> W2 (fp8 x4096) / W1 (fp6 e2m3 x8192)
//   blocks [8576,8672)  : d0inv[k] = 1/(sum_n h0[n]*W[n][k] + 1e-20)  (exact fp32)
// K=128 fragment layouts (lane l holds 32 contiguous contraction elements,
// k = (l>>4)*32 + j):
//   W2 (Phase B B-op, fp8 32B): byte = ((s*32 + w*4 + nt)*64 + l)*32 + j
//     element: n = w*64 + nt*16 + (l&15), k = s*128 + (l>>4)*32 + j
//   W1 (Phase A B-op, fp6 24B): frag = ((s*8 + w)*4 + c)*64 + l, byte = frag*24,
//     element j at bits [6j+5:6j]: kout = s*128 + w*16 + (l&15), n = c*128 + (l>>4)*32 + j
// ---------------------------------------------------------------------------
__global__ void prep_all(const float* __restrict__ x,
                         const float* __restrict__ W,
                         const float* __restrict__ h_init,
                         unsigned short* __restrict__ X2,
                         unsigned char* __restrict__ W1,
                         unsigned char* __restrict__ W2,
                         float* __restrict__ d0inv) {
    __shared__ float wsum[4];
    __shared__ float dred[8][32];
    const int bb = blockIdx.x;
    const int t  = threadIdx.x;

    if (bb < 8192) {
        // ---- x row normalize -> bf16, pre-scaled x16 (exact: power of 2)
        const int b = bb;
        const float4* r4 = reinterpret_cast<const float4*>(x + (size_t)b * NIN);
        float s = 0.f;
        float4 v0 = r4[t], v1 = r4[t + 256], v2 = r4[t + 512];
        s = v0.x + v0.y + v0.z + v0.w + v1.x + v1.y + v1.z + v1.w + v2.x + v2.y + v2.z + v2.w;
        #pragma unroll
        for (int off = 32; off > 0; off >>= 1) s += __shfl_down(s, off, 64);
        int w = t >> 6, l = t & 63;
        if (l == 0) wsum[w] = s;
        __syncthreads();
        float inv = 16.0f / (wsum[0] + wsum[1] + wsum[2] + wsum[3] + 1e-20f);
        unsigned short* orow = X2 + (size_t)b * NIN;
        #pragma unroll
        for (int c = 0; c < 3; ++c) {
            float4 v = (c == 0) ? v0 : (c == 1) ? v1 : v2;
            ushort4 o;
            o.x = f2bf(v.x * inv); o.y = f2bf(v.y * inv);
            o.z = f2bf(v.z * inv); o.w = f2bf(v.w * inv);
            *reinterpret_cast<ushort4*>(orow + (t + c * 256) * 4) = o;
        }
    } else if (bb < 8192 + 384) {
        int tt = (bb - 8192) * 256 + t;       // 0 .. 98303
        if (tt < 49152) {
            // ---- W2 fp8 x4096
            int l = tt & 63, g = tt >> 6;
            int s = g >> 5, rem = g & 31, w = rem >> 2, nt = rem & 3;
            int n = w * 64 + nt * 16 + (l & 15);
            int kbase = s * 128 + ((l >> 4) << 5);
            const float* src = W + (size_t)n * NIN + kbase;
            unsigned int words[8];
            #pragma unroll
            for (int q = 0; q < 8; ++q) {
                float v0 = src[q * 4 + 0] * 4096.0f, v1 = src[q * 4 + 1] * 4096.0f;
                float v2 = src[q * 4 + 2] * 4096.0f, v3 = src[q * 4 + 3] * 4096.0f;
                int pk = __builtin_amdgcn_cvt_pk_fp8_f32(v0, v1, 0, false);
                pk     = __builtin_amdgcn_cvt_pk_fp8_f32(v2, v3, pk, true);
                words[q] = (unsigned int)pk;
            }
            uint4* dst = reinterpret_cast<uint4*>(W2 + (size_t)tt * 32);
            dst[0] = *reinterpret_cast<uint4*>(&words[0]);
            dst[1] = *reinterpret_cast<uint4*>(&words[4]);
        } else {
            // ---- W1 fp6 e2m3 x8192 (24 B per fragment)
            int u = tt - 49152;
            int l = u & 63, g = u >> 6;
            int c = g & 3, sw = g >> 2;
            int w = sw & 7, s = sw >> 3;
            int kout = s * 128 + w * 16 + (l & 15);
            int nbase = c * 128 + ((l >> 4) << 5);
            float v[32];
            #pragma unroll
            for (int j = 0; j < 32; ++j)
                v[j] = W[(size_t)(nbase + j) * NIN + kout] * 8192.0f;
            unsigned int dw[6] = {0, 0, 0, 0, 0, 0};
            #pragma unroll
            for (int j = 0; j < 32; ++j) {
                unsigned c6 = enc_fp6(v[j]);
                int bit = 6 * j, di = bit >> 5, off = bit & 31;
                dw[di] |= c6 << off;
                if (off > 26) dw[di + 1] |= c6 >> (32 - off);
            }
            uint2* d2 = reinterpret_cast<uint2*>(W1 + (size_t)u * 24);
            d2[0] = make_uint2(dw[0], dw[1]);
            d2[1] = make_uint2(dw[2], dw[3]);
            d2[2] = make_uint2(dw[4], dw[5]);
        }
    } else {
        // ---- d0inv: block owns 32 k-cols; thread (kid = t&31, nsub = t>>5)
        int kb = bb - 8576;                   // 0..95
        int kid = t & 31, nsub = t >> 5;      // 8 n-chunks of 64
        int k = kb * 32 + kid;
        int n0 = nsub * 64;
        float s = 0.f;
        const float* p = W + (size_t)n0 * NIN + k;
        #pragma unroll 8
        for (int n = 0; n < 64; ++n) s += h_init[n0 + n] * p[(size_t)n * NIN];
        dred[nsub][kid] = s;
        __syncthreads();
        if (t < 32) {
            float sm = 1e-20f;
            #pragma unroll
            for (int j = 0; j < 8; ++j) sm += dred[j][t];
            d0inv[kb * 32 + t] = 1.0f / sm;
        }
    }
}

// ---------------------------------------------------------------------------
// Main kernel. 256 blocks x 512 threads (8 waves), 32 rows/block, 1 block/CU.
// Two-barrier slot structure; h master in LDS; Phase A fp8xfp6, Phase B fp8.
// ---------------------------------------------------------------------------
__global__ __launch_bounds__(512, 1) void nnmf_main(
    const unsigned short* __restrict__ X2,
    const unsigned char* __restrict__ W1,
    const unsigned char* __restrict__ W2,
    const float* __restrict__ d0inv,
    const float* __restrict__ h_init,
    float* __restrict__ out)
{
    __shared__ unsigned char  h8_lds[32 * 528];   // 16.9 KB (fp8 h, x256)
    __shared__ float          h32_lds[32 * 516];  // 66.0 KB (fp32 h master)
    __shared__ unsigned short x_lds[32 * 136];    //  8.7 KB
    __shared__ unsigned char  r8_lds[32 * 144];   //  4.6 KB (fp8 r, stride 144B)
    __shared__ float red[8][32];
    // total ~97.3 KB

    const int tid = threadIdx.x;
    const int w  = tid >> 6;        // wave 0..7
    const int l  = tid & 63;
    const int lo = l & 15;
    const int hi = l >> 4;          // 0..3
    const int b0 = blockIdx.x * 32;

    // fp32 h master init (LDS; each (row,col) owned by one thread at boundary)
    for (int idx = tid; idx < 32 * 512; idx += 512) {
        int r = idx >> 9, c = idx & 511;
        h32_lds[r * 516 + c] = h_init[c];
    }

    // x staging: thread -> (row, 16B chunk)
    const int xrow = tid >> 4, xcc = tid & 15;
    const uint4* xg = reinterpret_cast<const uint4*>(X2 + (size_t)(b0 + xrow) * NIN + xcc * 8);
    unsigned short* xdst = &x_lds[xrow * 136 + xcc * 8];

    // W pointers
    const unsigned char* w1base = W1 + ((size_t)(w * 4) * 64 + l) * 24;  // +s*49152 +c*1536 (fp6)
    const unsigned char* w2base = W2 + (size_t)w * 8192 + (size_t)l * 32; // +s*65536 +nt*2048 (fp8)

    // prime pipeline: x[0] -> LDS, x[1] -> reg
    *reinterpret_cast<uint4*>(xdst) = xg[0];
    uint4 xnext = xg[16];
    frag32 w1buf[4];                // Phase A B-frags fp6 (valid from it0 s==23 on)
    __syncthreads();

    const float DSCL = 4.76837158203125e-07f;  // 2^-21: undo h x2^8 * W1 x2^13
    const float TS   = 1.0f / 65536.0f;        // 2^-16: undo W2 x2^12 and x-r x2^4
    f32x4 tacc[2][4];

    for (int it = 0; it < 5; ++it) {
        #pragma unroll
        for (int m = 0; m < 2; ++m)
            #pragma unroll
            for (int nt = 0; nt < 4; ++nt)
                tacc[m][nt] = (f32x4){0.f, 0.f, 0.f, 0.f};

        for (int s = 0; s < 24; ++s) {
            const int sn  = (s + 1 == 24) ? 0 : s + 1;
            const int sn2 = (s + 2 >= 24) ? (s + 2 - 24) : s + 2;

            // ---- issue W2[s] loads (4 x 32B fp8 frags; consumed after barrier A)
            frag32 w2v[4];
            {
                const unsigned char* w2p = w2base + (size_t)s * 65536;
                #pragma unroll
                for (int nt = 0; nt < 4; ++nt) {
                    const uint4* p = reinterpret_cast<const uint4*>(w2p + nt * 2048);
                    w2v[nt].q[0] = p[0];
                    w2v[nt].q[1] = p[1];
                }
            }

            f32x4 d0 = {0,0,0,0}, d1 = {0,0,0,0};
            float dv = 0.f;
            if (it == 0) {
                dv = d0inv[s * 128 + w * 16 + lo];   // exact it0 denom reciprocal
            } else {
                // ---- Phase A: h fp8 (A) x W1 fp6 (B), minimal transients
                #pragma unroll
                for (int c = 0; c < 4; ++c) {
                    frag32 ha0, ha1;
                    const uint4* p0 = reinterpret_cast<const uint4*>(
                        &h8_lds[lo * 528 + c * 128 + hi * 32]);
                    const uint4* p1 = reinterpret_cast<const uint4*>(
                        &h8_lds[(16 + lo) * 528 + c * 128 + hi * 32]);
                    ha0.q[0] = p0[0]; ha0.q[1] = p0[1];
                    ha1.q[0] = p1[0]; ha1.q[1] = p1[1];
                    d0 = MFMA128_F6(ha0.v, w1buf[c].v, d0);
                    d1 = MFMA128_F6(ha1.v, w1buf[c].v, d1);
                }
            }

            // ---- r = x * rcp(denom + eps) -> fp8 in r8_lds  (x pre-scaled x16)
            #pragma unroll
            for (int i = 0; i < 4; ++i) {
                int row0 = hi * 4 + i;
                float x0 = bf2f(x_lds[row0 * 136 + w * 16 + lo]);
                float x1 = bf2f(x_lds[(16 + row0) * 136 + w * 16 + lo]);
                float r0, r1;
                if (it == 0) { r0 = x0 * dv; r1 = x1 * dv; }
                else {
                    r0 = x0 * __builtin_amdgcn_rcpf(fmaf(d0[i], DSCL, 1e-20f));
                    r1 = x1 * __builtin_amdgcn_rcpf(fmaf(d1[i], DSCL, 1e-20f));
                }
                int c0 = __builtin_amdgcn_cvt_pk_fp8_f32(r0, r0, 0, false);
                int c1 = __builtin_amdgcn_cvt_pk_fp8_f32(r1, r1, 0, false);
                r8_lds[row0 * 144 + w * 16 + lo] = (unsigned char)(c0 & 0xff);
                r8_lds[(16 + row0) * 144 + w * 16 + lo] = (unsigned char)(c1 & 0xff);
            }
            LDS_BARRIER();   // barrier A (LDS-only: global prefetches stay in flight)

            // ---- Phase B: r8 frags (fp8) x w2v (fp8)
            frag32 ra0, ra1;
            {
                const uint4* p0 = reinterpret_cast<const uint4*>(&r8_lds[lo * 144 + hi * 32]);
                const uint4* p1 = reinterpret_cast<const uint4*>(&r8_lds[(16 + lo) * 144 + hi * 32]);
                ra0.q[0] = p0[0]; ra0.q[1] = p0[1];
                ra1.q[0] = p1[0]; ra1.q[1] = p1[1];
            }
            #pragma unroll
            for (int nt = 0; nt < 2; ++nt) {
                tacc[0][nt] = MFMA128(ra0.v, w2v[nt].v, tacc[0][nt]);
                tacc[1][nt] = MFMA128(ra1.v, w2v[nt].v, tacc[1][nt]);
            }

            // ---- reload w1buf = W1[sn] fp6 (skip during it0 except last slot)
            if (it > 0 || s == 23) {
                const unsigned char* w1p = w1base + (size_t)sn * 49152;
                #pragma unroll
                for (int c = 0; c < 4; ++c)
                    load6(w1buf[c], w1p + c * 1536);
            }

            #pragma unroll
            for (int nt = 2; nt < 4; ++nt) {
                tacc[0][nt] = MFMA128(ra0.v, w2v[nt].v, tacc[0][nt]);
                tacc[1][nt] = MFMA128(ra1.v, w2v[nt].v, tacc[1][nt]);
            }

            // ---- stage x[s+1] (loaded last slot), issue x[s+2]
            *reinterpret_cast<uint4*>(xdst) = xnext;
            xnext = xg[(size_t)sn2 * 16];
            LDS_BARRIER();   // barrier B
        }

        // ---- boundary: h_new = normalize(h * (1 + t*2^-16)), fp32 master in LDS
        float hv_[2][4][4];
        float p[2][4];
        #pragma unroll
        for (int m = 0; m < 2; ++m)
            #pragma unroll
            for (int i = 0; i < 4; ++i) p[m][i] = 0.f;

        #pragma unroll
        for (int m = 0; m < 2; ++m)
            #pragma unroll
            for (int nt = 0; nt < 4; ++nt)
                #pragma unroll
                for (int i = 0; i < 4; ++i) {
                    int row = m * 16 + hi * 4 + i;
                    int col = w * 64 + nt * 16 + lo;
                    float hv = h32_lds[row * 516 + col];
                    float v = hv * (1.f + tacc[m][nt][i] * TS);  // EPSILON_0 = 1
                    hv_[m][nt][i] = v;
                    p[m][i] += v;
                }
        #pragma unroll
        for (int mask = 1; mask < 16; mask <<= 1)
            #pragma unroll
            for (int m = 0; m < 2; ++m)
                #pragma unroll
                for (int i = 0; i < 4; ++i)
                    p[m][i] += __shfl_xor(p[m][i], mask, 64);
        if (lo == 0) {
            #pragma unroll
            for (int m = 0; m < 2; ++m)
                #pragma unroll
                for (int i = 0; i < 4; ++i)
                    red[w][m * 16 + hi * 4 + i] = p[m][i];
        }
        __syncthreads();
        float inv[2][4];
        #pragma unroll
        for (int m = 0; m < 2; ++m)
            #pragma unroll
            for (int i = 0; i < 4; ++i) {
                int row = m * 16 + hi * 4 + i;
                float S = 0.f;
                #pragma unroll
                for (int ww = 0; ww < 8; ++ww) S += red[ww][row];
                inv[m][i] = 1.f / (S + 1e-20f);
            }

        if (it < 4) {
            #pragma unroll
            for (int m = 0; m < 2; ++m)
                #pragma unroll
                for (int nt = 0; nt < 4; ++nt)
                    #pragma unroll
                    for (int i = 0; i < 4; ++i) {
                        int row = m * 16 + hi * 4 + i;
                        int col = w * 64 + nt * 16 + lo;
                        float hv = hv_[m][nt][i] * inv[m][i];
                        h32_lds[row * 516 + col] = hv;
                        int c = __builtin_amdgcn_cvt_pk_fp8_f32(hv * 256.0f, hv * 256.0f, 0, false);
                        h8_lds[row * 528 + col] = (unsigned char)(c & 0xff);
                    }
            __syncthreads();
        } else {
            #pragma unroll
            for (int m = 0; m < 2; ++m)
                #pragma unroll
                for (int nt = 0; nt < 4; ++nt)
                    #pragma unroll
                    for (int i = 0; i < 4; ++i) {
                        int row = m * 16 + hi * 4 + i;
                        int col = w * 64 + nt * 16 + lo;
                        out[(size_t)(b0 + row) * 512 + col] = hv_[m][nt][i] * inv[m][i];
                    }
        }
    }
}

extern "C" void kernel_launch(void* const* d_in, const int* in_sizes, int n_in,
                              void* d_out, int out_size, void* d_ws, size_t ws_size,
                              hipStream_t stream) {
    const float* x   = (const float*)d_in[0];   // [8192][3072]
    const float* wgt = (const float*)d_in[1];   // [512][3072]
    const float* h0  = (const float*)d_in[2];   // [512]
    float* out = (float*)d_out;

    // ws: X2 bf16 50,331,648 | W1 fp6 1,179,648 | W2 fp8 1,572,864 | d0inv 12,288
    unsigned short* X2 = (unsigned short*)d_ws;
    unsigned char*  W1 = (unsigned char*)((char*)d_ws + 50331648);
    unsigned char*  W2 = (unsigned char*)((char*)d_ws + 51511296);
    float* d0inv       = (float*)((char*)d_ws + 53084160);

    prep_all<<<8672, 256, 0, stream>>>(x, wgt, h0, X2, W1, W2, d0inv);
    nnmf_main<<<256, 512, 0, stream>>>(X2, W1, W2, d0inv, h0, out);
}